// Round 6
// baseline (378.764 us; speedup 1.0000x reference)
//
#include <hip/hip_runtime.h>
#include <stdint.h>

#define BATCH 8
#define NC 80
#define NA1 8112
#define NA2 2028
#define NA3 507
#define NTOT 10647
#define NTILES 84            /* ceil(NTOT/128) */
#define KSEL 256
#define MAXPC 100
#define MAXTOT 100
#define NEGV -1000000000.0f
#define SCTHR 0.3f
#define IOUTHR 0.5f
#define M2 (NC * KSEL)       /* 20480 per image */
#define MAXCAND 8000         /* <=100 kept per class * 80 classes */
#define KEYTHR 0xBE99999Au   /* okey(0.3f) — candidate iff key > KEYTHR */
#define KEYBASE 0xBE99999Bu  /* rebased keys fit in 24 bits (max 0x00E66665) */

typedef unsigned long long ull;

// static device scratch, fully rewritten every launch (g_cnt zeroed by zero_cnt)
__device__ ull g_cand[(size_t)BATCH * NC * NTOT];   // 54.5 MB worst case
__device__ unsigned g_cnt[BATCH * NC];
__device__ float g_s[BATCH * NC * KSEL];
__device__ int   g_n[BATCH * NC * KSEL];

__device__ __forceinline__ unsigned okey(float f) {
  unsigned u = __float_as_uint(f);
  return u ^ ((unsigned)((int)u >> 31) | 0x80000000u);
}
__device__ __forceinline__ float inv_okey(unsigned k) {
  unsigned u = (k & 0x80000000u) ? (k ^ 0x80000000u) : ~k;
  return __uint_as_float(u);
}

// inclusive suffix sum across a 64-lane wave
__device__ __forceinline__ unsigned wave_sufscan(unsigned v, int lane) {
  #pragma unroll
  for (int off = 1; off < 64; off <<= 1) {
    unsigned t = __shfl_down(v, off, 64);
    if (lane + off < 64) v += t;
  }
  return v;
}

// top-kwant threshold over rebased 24-bit keys; 3 passes, per-wave sub-histograms,
// wave-shfl suffix scan (no barrier ping-pong). blockDim.x == 256 required.
template <typename F>
__device__ void radix_sel24(F getkey, int cnt, unsigned kwant,
                            unsigned* hist4, unsigned* suf, unsigned* s_sel,
                            unsigned* wtot, unsigned& T_out, unsigned& need_out)
{
  const int tid = threadIdx.x;
  const int lane = tid & 63, wv = tid >> 6;
  const int wb = wv << 8;
  unsigned need = kwant, prefix = 0;
  for (int shift = 16; shift >= 0; shift -= 8) {
    hist4[tid] = 0; hist4[tid + 256] = 0; hist4[tid + 512] = 0; hist4[tid + 768] = 0;
    __syncthreads();
    unsigned maskhi = (shift == 16) ? 0u : (0x00FFFFFFu ^ ((1u << (shift + 8)) - 1u));
    for (int i = tid; i < cnt; i += 256) {
      unsigned k = getkey(i);
      if ((k & maskhi) == prefix) atomicAdd(&hist4[wb + ((k >> shift) & 255u)], 1u);
    }
    __syncthreads();
    unsigned v = hist4[tid] + hist4[tid + 256] + hist4[tid + 512] + hist4[tid + 768];
    v = wave_sufscan(v, lane);
    if (lane == 0) wtot[wv] = v;
    __syncthreads();
    unsigned add = 0;
    for (int w = wv + 1; w < 4; ++w) add += wtot[w];
    v += add;
    suf[tid] = v;
    __syncthreads();
    unsigned nxt = (tid == 255) ? 0u : suf[tid + 1];
    if (v >= need && nxt < need) {
      s_sel[0] = prefix | ((unsigned)tid << shift);
      s_sel[1] = need - nxt;
    }
    __syncthreads();
    prefix = s_sel[0];
    need = s_sel[1];
    __syncthreads();
  }
  T_out = prefix;
  need_out = need;
}

__global__ void zero_cnt() {
  int i = blockIdx.x * 256 + threadIdx.x;
  if (i < BATCH * NC) g_cnt[i] = 0;
}

// Kernel A: coalesced score compute + per-class threshold compaction (ballot-aggregated)
__global__ __launch_bounds__(256)
void score_compact(const float* __restrict__ c1, const float* __restrict__ p1,
                   const float* __restrict__ c2, const float* __restrict__ p2,
                   const float* __restrict__ c3, const float* __restrict__ p3)
{
  const int tid = threadIdx.x;
  const int b = blockIdx.x / NTILES;
  const int tile = blockIdx.x % NTILES;
  const int n0 = tile * 128;

  __shared__ unsigned skey[128 * 81];   // odd stride: conflict-free both phases
  __shared__ float sconf[128];

  if (tid < 128) {
    int ng = n0 + tid;
    float cf = 0.0f;
    if (ng < NTOT) {
      if (ng < NA1)            cf = c1[b * NA1 + ng];
      else if (ng < NA1 + NA2) cf = c2[b * NA2 + ng - NA1];
      else                     cf = c3[b * NA3 + ng - NA1 - NA2];
    }
    sconf[tid] = cf;
  }
  __syncthreads();

  for (int e4 = tid; e4 < 2560; e4 += 256) {
    int a = e4 / 20;
    int cls0 = (e4 % 20) * 4;
    int ng = n0 + a;
    unsigned k0 = 0, k1 = 0, k2 = 0, k3 = 0;
    if (ng < NTOT) {
      const float* pp; int nl;
      if (ng < NA1)            { pp = p1 + (size_t)b * NA1 * NC; nl = ng; }
      else if (ng < NA1 + NA2) { pp = p2 + (size_t)b * NA2 * NC; nl = ng - NA1; }
      else                     { pp = p3 + (size_t)b * NA3 * NC; nl = ng - NA1 - NA2; }
      float4 pv = *(const float4*)(pp + (size_t)nl * NC + cls0);
      float cf = sconf[a];
      k0 = okey(pv.x * cf); k1 = okey(pv.y * cf);
      k2 = okey(pv.z * cf); k3 = okey(pv.w * cf);
    }
    skey[a * 81 + cls0 + 0] = k0;
    skey[a * 81 + cls0 + 1] = k1;
    skey[a * 81 + cls0 + 2] = k2;
    skey[a * 81 + cls0 + 3] = k3;
  }
  __syncthreads();

  // two classes at a time: waves 0-1 -> even class, waves 2-3 -> odd class
  const int half = tid >> 7;
  const int a = tid & 127;
  const int lane = tid & 63;
  const int ng = n0 + a;
  for (int it = 0; it < 40; ++it) {
    int c = it * 2 + half;
    unsigned k = skey[a * 81 + c];
    bool pred = (k > KEYTHR) && (ng < NTOT);
    ull m = __ballot(pred);
    if (m != 0ull) {
      int ldr = __ffsll(m) - 1;
      unsigned base = 0;
      if (lane == ldr) base = atomicAdd(&g_cnt[b * NC + c], (unsigned)__popcll(m));
      base = __shfl(base, ldr, 64);
      if (pred) {
        unsigned pos = base + (unsigned)__popcll(m & ((1ull << lane) - 1ull));
        g_cand[(size_t)(b * NC + c) * NTOT + pos] = ((ull)k << 32) | (unsigned)(~ng);
      }
    }
  }
}

// Kernel B: per (b,c) top-256 select + sort + NMS. LDS ~16KB -> high occupancy.
__global__ __launch_bounds__(256)
void nms_per_class(const float* __restrict__ b1, const float* __restrict__ b2,
                   const float* __restrict__ b3)
{
  const int tid = threadIdx.x;
  const int bc = blockIdx.x;
  const int b = bc / NC;

  __shared__ ull supp[KSEL * 4];        // 8KB; radix hist/suf alias into it
  __shared__ ull cand[KSEL];
  __shared__ float4 cbox[KSEL];
  __shared__ float csc[KSEL];
  __shared__ unsigned char keptf[KSEL];
  __shared__ unsigned s_sel[2];
  __shared__ unsigned wtot[4];
  __shared__ int s_cgt, s_ceq;
  unsigned* hist4 = (unsigned*)supp;          // 1024 u32
  unsigned* suf = (unsigned*)supp + 1024;     // 256 u32  (<= 8KB total)

  const ull* src = g_cand + (size_t)bc * NTOT;
  const int cnt = (int)g_cnt[bc];

  if (cnt <= KSEL) {
    cand[tid] = (tid < cnt) ? src[tid] : 0ull;
  } else {
    unsigned T, need;
    auto getk = [&](int i) { return (unsigned)(src[i] >> 32) - KEYBASE; };
    radix_sel24(getk, cnt, KSEL, hist4, suf, s_sel, wtot, T, need);
    if (tid == 0) { s_cgt = 0; s_ceq = 0; }
    __syncthreads();
    const int ngt = KSEL - (int)need;
    for (int i = tid; i < cnt; i += 256) {
      ull v = src[i];
      unsigned k = (unsigned)(v >> 32) - KEYBASE;
      if (k > T) {
        int p = atomicAdd(&s_cgt, 1);
        cand[p] = v;
      } else if (k == T) {
        int p = atomicAdd(&s_ceq, 1);
        if (p < (int)need) cand[ngt + p] = v;
      }
    }
  }
  __syncthreads();

  // bitonic sort 256 descending by (key, ~n); zero pads sink
  for (int kk = 2; kk <= KSEL; kk <<= 1) {
    for (int j = kk >> 1; j > 0; j >>= 1) {
      int ixj = tid ^ j;
      if (ixj > tid) {
        ull a = cand[tid], cc = cand[ixj];
        if (((tid & kk) == 0) ? (a < cc) : (a > cc)) { cand[tid] = cc; cand[ixj] = a; }
      }
      __syncthreads();
    }
  }

  int myn = 0;
  {
    ull ck = cand[tid];
    float sc = -1e30f;
    float4 bx = make_float4(0.f, 0.f, 0.f, 0.f);
    if (ck != 0ull) {
      myn = (int)(~(unsigned)ck);
      sc = inv_okey((unsigned)(ck >> 32));
      const float* bp;
      if (myn < NA1)            bp = b1 + (size_t)(b * NA1 + myn) * 4;
      else if (myn < NA1 + NA2) bp = b2 + (size_t)(b * NA2 + (myn - NA1)) * 4;
      else                      bp = b3 + (size_t)(b * NA3 + (myn - NA1 - NA2)) * 4;
      bx = make_float4(bp[0], bp[1], bp[2], bp[3]);
    }
    csc[tid] = sc;
    cbox[tid] = bx;
  }
  __syncthreads();

  // suppression bitmask rows (thread i: bits j with iou(i,j)>thr, j>i)
  {
    const float4 mb = cbox[tid];
    const float myarea = (mb.z - mb.x) * (mb.w - mb.y);
    ull m0 = 0, m1 = 0, m2 = 0, m3 = 0;
    for (int j = 0; j < KSEL; ++j) {
      float4 bj = cbox[j];            // LDS broadcast
      float ja = (bj.z - bj.x) * (bj.w - bj.y);
      float iy = fmaxf(fminf(bj.z, mb.z) - fmaxf(bj.x, mb.x), 0.0f);
      float ix = fmaxf(fminf(bj.w, mb.w) - fmaxf(bj.y, mb.y), 0.0f);
      float inter = iy * ix;
      float uni = ja + myarea - inter;
      bool sup = (j > tid) && (uni > 0.0f) && (inter > IOUTHR * uni);
      ull bit = sup ? (1ull << (j & 63)) : 0ull;
      if ((j >> 6) == 0) m0 |= bit; else if ((j >> 6) == 1) m1 |= bit;
      else if ((j >> 6) == 2) m2 |= bit; else m3 |= bit;
    }
    supp[tid * 4 + 0] = m0; supp[tid * 4 + 1] = m1;
    supp[tid * 4 + 2] = m2; supp[tid * 4 + 3] = m3;
  }
  __syncthreads();

  if (tid == 0) {   // sequential greedy scan over bitmasks
    ull keep0 = ~0ull, keep1 = ~0ull, keep2 = ~0ull, keep3 = ~0ull;
    int run = 0;
    for (int i = 0; i < KSEL; ++i) {
      ull kw = (i < 64) ? keep0 : (i < 128) ? keep1 : (i < 192) ? keep2 : keep3;
      bool cur = ((kw >> (i & 63)) & 1ull) && (csc[i] > SCTHR);
      unsigned char kf = 0;
      if (cur) {
        keep0 &= ~supp[i * 4 + 0]; keep1 &= ~supp[i * 4 + 1];
        keep2 &= ~supp[i * 4 + 2]; keep3 &= ~supp[i * 4 + 3];
        if (++run <= MAXPC) kf = 1;
      }
      keptf[i] = kf;
    }
  }
  __syncthreads();

  const size_t base = (size_t)bc * KSEL + tid;
  g_s[base] = keptf[tid] ? csc[tid] : NEGV;
  g_n[base] = myn;
}

// Kernel C: per-image top-100 merge + output
__global__ __launch_bounds__(256)
void nms_final(const float* __restrict__ b1, const float* __restrict__ b2,
               const float* __restrict__ b3, float* __restrict__ out)
{
  const int tid = threadIdx.x;
  const int b = blockIdx.x;

  __shared__ unsigned lk[MAXCAND];
  __shared__ unsigned short lfi[MAXCAND];
  __shared__ unsigned hist4[1024];
  __shared__ unsigned suf[256];
  __shared__ unsigned s_sel[2];
  __shared__ unsigned wtot[4];
  __shared__ int s_cnt, s_cgt, s_ceq, s_nv;
  __shared__ ull cand[128];

  if (tid == 0) s_cnt = 0;
  __syncthreads();

  const float* s = g_s + (size_t)b * M2;
  for (int base2 = 0; base2 < M2; base2 += 256) {
    int fi = base2 + tid;
    float sc = s[fi];
    bool pred = sc > SCTHR;
    ull mask = __ballot(pred);
    if (mask != 0ULL) {
      int lane = tid & 63;
      int ldr = __ffsll(mask) - 1;
      int wb = 0;
      if (lane == ldr) wb = atomicAdd(&s_cnt, __popcll(mask));
      wb = __shfl(wb, ldr, 64);
      if (pred) {
        int pos = wb + __popcll(mask & ((1ULL << lane) - 1ULL));
        lk[pos] = okey(sc);
        lfi[pos] = (unsigned short)fi;
      }
    }
  }
  __syncthreads();
  const int cnt = s_cnt;

  if (tid < 128) cand[tid] = 0ULL;
  __syncthreads();

  if (cnt <= MAXTOT) {
    if (tid < cnt)
      cand[tid] = ((ull)lk[tid] << 16) | (unsigned)((~lfi[tid]) & 0xFFFF);
    __syncthreads();
  } else {
    unsigned T, need;
    auto getk = [&](int i) { return lk[i] - KEYBASE; };
    radix_sel24(getk, cnt, MAXTOT, hist4, suf, s_sel, wtot, T, need);
    if (tid == 0) { s_cgt = 0; s_ceq = 0; }
    __syncthreads();
    const int ngt = MAXTOT - (int)need;
    for (int i = tid; i < cnt; i += 256) {
      unsigned k = lk[i] - KEYBASE;
      if (k > T) {
        int p = atomicAdd(&s_cgt, 1);
        cand[p] = ((ull)lk[i] << 16) | (unsigned)((~lfi[i]) & 0xFFFF);
      } else if (k == T) {
        int p = atomicAdd(&s_ceq, 1);
        if (p < (int)need) cand[ngt + p] = ((ull)lk[i] << 16) | (unsigned)((~lfi[i]) & 0xFFFF);
      }
    }
    __syncthreads();
  }

  for (int kk = 2; kk <= 128; kk <<= 1) {
    for (int j = kk >> 1; j > 0; j >>= 1) {
      if (tid < 128) {
        int ixj = tid ^ j;
        if (ixj > tid) {
          ull a = cand[tid], cc = cand[ixj];
          if (((tid & kk) == 0) ? (a < cc) : (a > cc)) { cand[tid] = cc; cand[ixj] = a; }
        }
      }
      __syncthreads();
    }
  }

  if (tid == 0) s_nv = 0;
  __syncthreads();

  if (tid < MAXTOT) {
    ull ck = cand[tid];
    float o0 = 0.f, o1 = 0.f, o2 = 0.f, o3 = 0.f, osc = 0.f, ocl = 0.f;
    if (ck != 0ULL) {
      unsigned k = (unsigned)(ck >> 16);
      int fi = (int)((~(unsigned)ck) & 0xFFFFu);
      float sc = inv_okey(k);
      if (sc > SCTHR) {
        int cls = fi >> 8;
        int n = g_n[(size_t)b * M2 + fi];
        const float* bp;
        if (n < NA1)            bp = b1 + (size_t)(b * NA1 + n) * 4;
        else if (n < NA1 + NA2) bp = b2 + (size_t)(b * NA2 + (n - NA1)) * 4;
        else                    bp = b3 + (size_t)(b * NA3 + (n - NA1 - NA2)) * 4;
        o0 = fminf(fmaxf(bp[0], 0.0f), 1.0f);
        o1 = fminf(fmaxf(bp[1], 0.0f), 1.0f);
        o2 = fminf(fmaxf(bp[2], 0.0f), 1.0f);
        o3 = fminf(fmaxf(bp[3], 0.0f), 1.0f);
        osc = sc;
        ocl = (float)cls;
        atomicAdd(&s_nv, 1);
      }
    }
    int oi = b * MAXTOT + tid;
    out[(size_t)oi * 4 + 0] = o0;
    out[(size_t)oi * 4 + 1] = o1;
    out[(size_t)oi * 4 + 2] = o2;
    out[(size_t)oi * 4 + 3] = o3;
    out[BATCH * MAXTOT * 4 + oi] = osc;
    out[BATCH * MAXTOT * 5 + oi] = ocl;
  }
  __syncthreads();
  if (tid == 0) out[BATCH * MAXTOT * 6 + b] = (float)s_nv;
}

extern "C" void kernel_launch(void* const* d_in, const int* in_sizes, int n_in,
                              void* d_out, int out_size, void* d_ws, size_t ws_size,
                              hipStream_t stream) {
  const float* b1 = (const float*)d_in[0];
  const float* c1 = (const float*)d_in[1];
  const float* p1 = (const float*)d_in[2];
  const float* b2 = (const float*)d_in[3];
  const float* c2 = (const float*)d_in[4];
  const float* p2 = (const float*)d_in[5];
  const float* b3 = (const float*)d_in[6];
  const float* c3 = (const float*)d_in[7];
  const float* p3 = (const float*)d_in[8];
  (void)in_sizes; (void)n_in; (void)out_size; (void)d_ws; (void)ws_size;

  zero_cnt<<<dim3(3), dim3(256), 0, stream>>>();
  score_compact<<<dim3(BATCH * NTILES), dim3(256), 0, stream>>>(c1, p1, c2, p2, c3, p3);
  nms_per_class<<<dim3(BATCH * NC), dim3(256), 0, stream>>>(b1, b2, b3);
  nms_final<<<dim3(BATCH), dim3(256), 0, stream>>>(b1, b2, b3, (float*)d_out);
}

// Round 8
// 241.701 us; speedup vs baseline: 1.5671x; 1.5671x over previous
//
#include <hip/hip_runtime.h>
#include <stdint.h>

#define BATCH 8
#define NC 80
#define NA1 8112
#define NA2 2028
#define NA3 507
#define NTOT 10647
#define TILE 64
#define NTILES 167           /* ceil(10647/64) */
#define NSLOTS (NTILES*TILE) /* 10688 */
#define KSEL 256
#define MAXPC 100
#define MAXTOT 100
#define SCTHR 0.3f
#define IOUTHR 0.5f
#define KEYTHR 0xBE99999Au   /* okey(0.3f): candidate iff key > KEYTHR */
#define KEYBASE 0xBE99999Bu  /* rebased keys fit in 24 bits */
#define STAGE_CAP 5120

typedef unsigned long long ull;

// static device scratch; every word that is read was written THIS launch
__device__ ull g_cand[(size_t)BATCH * NC * NSLOTS];   // 54.7 MB
__device__ unsigned g_tcnt[BATCH * NC * NTILES];      // per (class,tile) counts
__device__ ull g_ks[BATCH * NC * MAXPC];              // per-class kept, packed
__device__ unsigned g_kcnt[BATCH * NC];
__device__ ull g_ms[BATCH * 10 * MAXTOT];             // per class-group top-100
__device__ unsigned g_mcnt[BATCH * 10];

__device__ __forceinline__ unsigned okey(float f) {
  unsigned u = __float_as_uint(f);
  return u ^ ((unsigned)((int)u >> 31) | 0x80000000u);
}
__device__ __forceinline__ float inv_okey(unsigned k) {
  unsigned u = (k & 0x80000000u) ? (k ^ 0x80000000u) : ~k;
  return __uint_as_float(u);
}
__device__ __forceinline__ ull shflxor64(ull v, int m) {
  int lo = __shfl_xor((int)(unsigned)v, m, 64);
  int hi = __shfl_xor((int)(unsigned)(v >> 32), m, 64);
  return ((ull)(unsigned)hi << 32) | (unsigned)lo;
}
__device__ __forceinline__ ull bcast64(ull v, int src) {
  int lo = __shfl((int)(unsigned)v, src, 64);
  int hi = __shfl((int)(unsigned)(v >> 32), src, 64);
  return ((ull)(unsigned)hi << 32) | (unsigned)lo;
}
__device__ __forceinline__ unsigned wave_sufscan(unsigned v, int lane) {
  #pragma unroll
  for (int off = 1; off < 64; off <<= 1) {
    unsigned t = __shfl_down(v, off, 64);
    if (lane + off < 64) v += t;
  }
  return v;
}

// top-kwant threshold over rebased 24-bit keys. getkey returns 0xFFFFFFFF = skip.
template <typename F>
__device__ void radix_sel24(F getkey, int n, unsigned kwant,
                            unsigned* hist4, unsigned* suf,
                            unsigned* s_sel, unsigned* wtot,
                            unsigned& T_out, unsigned& need_out)
{
  const int tid = threadIdx.x;
  const int lane = tid & 63, wv = tid >> 6;
  const int wb = wv << 8;
  unsigned need = kwant, prefix = 0;
  for (int shift = 16; shift >= 0; shift -= 8) {
    hist4[tid] = 0; hist4[tid + 256] = 0; hist4[tid + 512] = 0; hist4[tid + 768] = 0;
    __syncthreads();
    unsigned maskhi = (shift == 16) ? 0u : (0x00FFFFFFu ^ ((1u << (shift + 8)) - 1u));
    for (int i = tid; i < n; i += 256) {
      unsigned k = getkey(i);
      if (k != 0xFFFFFFFFu && (k & maskhi) == prefix)
        atomicAdd(&hist4[wb + ((k >> shift) & 255u)], 1u);
    }
    __syncthreads();
    unsigned v = hist4[tid] + hist4[tid + 256] + hist4[tid + 512] + hist4[tid + 768];
    v = wave_sufscan(v, lane);
    if (lane == 0) wtot[wv] = v;
    __syncthreads();
    unsigned add = 0;
    for (int w = wv + 1; w < 4; ++w) add += wtot[w];
    v += add;
    suf[tid] = v;
    __syncthreads();
    unsigned nxt = (tid == 255) ? 0u : suf[tid + 1];
    if (v >= need && nxt < need) {
      s_sel[0] = prefix | ((unsigned)tid << shift);
      s_sel[1] = need - nxt;
    }
    __syncthreads();
    prefix = s_sel[0]; need = s_sel[1];
    __syncthreads();
  }
  T_out = prefix; need_out = need;
}

// ---------- Kernel A: scores + per-(class,tile) compaction, no atomics ----------
__global__ __launch_bounds__(256)
void score_compact(const float* __restrict__ c1, const float* __restrict__ p1,
                   const float* __restrict__ c2, const float* __restrict__ p2,
                   const float* __restrict__ c3, const float* __restrict__ p3)
{
  const int tid = threadIdx.x;
  const int b = blockIdx.x / NTILES;
  const int t = blockIdx.x % NTILES;
  const int n0 = t * TILE;

  __shared__ float sp[TILE * 81];   // raw p, stride 81: conflict-free column reads

  // coalesced p stage: 64 anchors x 20 float4
  for (int e4 = tid; e4 < TILE * 20; e4 += 256) {
    int a = e4 / 20;
    int c4 = (e4 - a * 20) * 4;
    int ng = n0 + a;
    if (ng < NTOT) {
      const float* pp; int nl;
      if (ng < NA1)            { pp = p1 + (size_t)b * NA1 * NC; nl = ng; }
      else if (ng < NA1 + NA2) { pp = p2 + (size_t)b * NA2 * NC; nl = ng - NA1; }
      else                     { pp = p3 + (size_t)b * NA3 * NC; nl = ng - NA1 - NA2; }
      float4 pv = *(const float4*)(pp + (size_t)nl * NC + c4);
      sp[a * 81 + c4 + 0] = pv.x; sp[a * 81 + c4 + 1] = pv.y;
      sp[a * 81 + c4 + 2] = pv.z; sp[a * 81 + c4 + 3] = pv.w;
    }
  }
  __syncthreads();

  const int wv = tid >> 6, lane = tid & 63;
  const int ng = n0 + lane;
  const bool av = ng < NTOT;
  float cf = 0.0f;
  if (av) {
    if (ng < NA1)            cf = c1[b * NA1 + ng];
    else if (ng < NA1 + NA2) cf = c2[b * NA2 + ng - NA1];
    else                     cf = c3[b * NA3 + ng - NA1 - NA2];
  }
  for (int k = 0; k < 20; ++k) {
    int c = wv + 4 * k;                        // wave w owns classes w, w+4, ...
    float pv = av ? sp[lane * 81 + c] : 0.0f;
    unsigned key = okey(pv * cf);
    bool pred = av && (key > KEYTHR);
    ull m = __ballot(pred);
    if (pred) {
      unsigned pos = (unsigned)__popcll(m & ((1ull << lane) - 1ull));
      g_cand[((size_t)(b * NC + c) * NTILES + t) * TILE + pos] =
          ((ull)key << 32) | (unsigned)(~ng);
    }
    if (lane == 0) g_tcnt[(b * NC + c) * NTILES + t] = (unsigned)__popcll(m);
  }
}

// ---------- Kernel B: per (b,c) top-256 + sort + NMS ----------
__global__ __launch_bounds__(256)
void nms_per_class(const float* __restrict__ b1, const float* __restrict__ b2,
                   const float* __restrict__ b3)
{
  const int tid = threadIdx.x;
  const int lane = tid & 63, wv = tid >> 6;
  const int bc = blockIdx.x;
  const int b = bc / NC;
  const int c = bc - b * NC;

  __shared__ unsigned ckey[STAGE_CAP];          // 20 KB
  __shared__ unsigned short cslot[STAGE_CAP];   // 10 KB
  __shared__ ull uSupp[KSEL * 5];               // 10 KB: supp rows; aliases radix hist/suf
  __shared__ float4 cbox[KSEL];                 // 4 KB: first 1.4 KB aliases tc/off
  __shared__ ull cand[KSEL];                    // 2 KB
  __shared__ ull kw[4], kfw[4];
  __shared__ unsigned s_sel[2], wtot[4];
  __shared__ int s_cgt, s_ceq;

  ull* supp = uSupp;                            // stride 5
  unsigned* hist4 = (unsigned*)uSupp;           // 1024 u32
  unsigned* suf = (unsigned*)uSupp + 1024;      // 256 u32
  unsigned* tc = (unsigned*)cbox;               // [0..167)
  unsigned* off = (unsigned*)cbox + 168;        // [0..168)

  const ull* crow = g_cand + (size_t)bc * NSLOTS;
  const unsigned* trow = g_tcnt + bc * NTILES;

  cand[tid] = 0ull;
  if (tid < NTILES) tc[tid] = trow[tid];
  __syncthreads();

  if (wv == 0) {                                // exclusive prefix over 167 counts
    unsigned carry = 0;
    for (int ch = 0; ch < 3; ++ch) {
      int idx = ch * 64 + lane;
      unsigned x = (idx < NTILES) ? tc[idx] : 0u;
      unsigned v = x;
      #pragma unroll
      for (int o = 1; o < 64; o <<= 1) {
        unsigned t2 = __shfl_up(v, o, 64);
        if (lane >= o) v += t2;
      }
      if (idx < NTILES) off[idx] = carry + v - x;
      carry += (unsigned)__shfl((int)v, 63, 64);
    }
    if (lane == 0) off[NTILES] = carry;
  }
  __syncthreads();
  const int cnt = (int)off[NTILES];
  const bool staged = (cnt > KSEL) && (cnt <= STAGE_CAP);

  // staging pass over slots
  for (int s = tid; s < NSLOTS; s += 256) {
    int t = s >> 6, j = s & 63;
    if (j < (int)tc[t]) {
      if (cnt <= KSEL) {
        cand[off[t] + j] = crow[s];
      } else if (staged) {
        int pos = off[t] + j;
        ckey[pos] = (unsigned)(crow[s] >> 32);
        cslot[pos] = (unsigned short)s;
      }
    }
  }
  __syncthreads();

  if (cnt > KSEL) {
    unsigned T, need;
    if (staged) {
      auto gk = [&](int i) { return ckey[i] - KEYBASE; };
      radix_sel24(gk, cnt, KSEL, hist4, suf, s_sel, wtot, T, need);
    } else {
      auto gk = [&](int s) {
        int t = s >> 6, j = s & 63;
        return (j < (int)tc[t]) ? ((unsigned)(crow[s] >> 32) - KEYBASE) : 0xFFFFFFFFu;
      };
      radix_sel24(gk, NSLOTS, KSEL, hist4, suf, s_sel, wtot, T, need);
    }
    if (tid == 0) { s_cgt = 0; s_ceq = 0; }
    __syncthreads();
    const int ngt = KSEL - (int)need;
    if (staged) {
      for (int i = tid; i < cnt; i += 256) {
        unsigned k = ckey[i] - KEYBASE;
        if (k > T) cand[atomicAdd(&s_cgt, 1)] = crow[cslot[i]];
        else if (k == T) { int p = atomicAdd(&s_ceq, 1); if (p < (int)need) cand[ngt + p] = crow[cslot[i]]; }
      }
    } else {
      for (int s = tid; s < NSLOTS; s += 256) {
        int t = s >> 6, j = s & 63;
        if (j < (int)tc[t]) {
          ull v = crow[s];
          unsigned k = (unsigned)(v >> 32) - KEYBASE;
          if (k > T) cand[atomicAdd(&s_cgt, 1)] = v;
          else if (k == T) { int p = atomicAdd(&s_ceq, 1); if (p < (int)need) cand[ngt + p] = v; }
        }
      }
    }
  }
  __syncthreads();

  // bitonic sort 256 descending: registers + shfl; LDS only for j>=64
  ull v = cand[tid];
  for (int kk = 2; kk <= KSEL; kk <<= 1) {
    for (int j = kk >> 1; j > 0; j >>= 1) {
      ull o;
      if (j >= 64) {
        cand[tid] = v;
        __syncthreads();
        o = cand[tid ^ j];
        __syncthreads();
      } else {
        o = shflxor64(v, j);
      }
      bool keep_max = (((tid & j) == 0) == ((tid & kk) == 0));
      v = keep_max ? (v > o ? v : o) : (v < o ? v : o);
    }
  }
  __syncthreads();   // tc/off dead from here; cbox reuse is safe

  int myn = 0;
  {
    float4 bx = make_float4(0.f, 0.f, 0.f, 0.f);
    if (v != 0ull) {
      myn = (int)(~(unsigned)v);
      const float* bp;
      if (myn < NA1)            bp = b1 + (size_t)(b * NA1 + myn) * 4;
      else if (myn < NA1 + NA2) bp = b2 + (size_t)(b * NA2 + (myn - NA1)) * 4;
      else                      bp = b3 + (size_t)(b * NA3 + (myn - NA1 - NA2)) * 4;
      bx = make_float4(bp[0], bp[1], bp[2], bp[3]);
    }
    cbox[tid] = bx;
  }
  ull mvalid = __ballot(v != 0ull);
  if (lane == 0) kw[wv] = mvalid;
  __syncthreads();

  // suppression rows
  {
    const float4 mb = cbox[tid];
    const float myarea = (mb.z - mb.x) * (mb.w - mb.y);
    ull m0 = 0, m1 = 0, m2 = 0, m3 = 0;
    for (int j = 0; j < KSEL; ++j) {
      float4 bj = cbox[j];
      float ja = (bj.z - bj.x) * (bj.w - bj.y);
      float iy = fmaxf(fminf(bj.z, mb.z) - fmaxf(bj.x, mb.x), 0.0f);
      float ix = fmaxf(fminf(bj.w, mb.w) - fmaxf(bj.y, mb.y), 0.0f);
      float inter = iy * ix;
      float uni = ja + myarea - inter;
      bool sup = (j > tid) && (uni > 0.0f) && (inter > IOUTHR * uni);
      ull bit = sup ? (1ull << (j & 63)) : 0ull;
      if ((j >> 6) == 0) m0 |= bit; else if ((j >> 6) == 1) m1 |= bit;
      else if ((j >> 6) == 2) m2 |= bit; else m3 |= bit;
    }
    supp[tid * 5 + 0] = m0; supp[tid * 5 + 1] = m1;
    supp[tid * 5 + 2] = m2; supp[tid * 5 + 3] = m3;
  }
  __syncthreads();

  // greedy scan, wave 0, all in registers (shfl broadcast, no LDS in the chain)
  if (wv == 0) {
    ull r0[4], r1[4], r2[4], r3[4];
    #pragma unroll
    for (int w = 0; w < 4; ++w) {
      r0[w] = supp[(lane) * 5 + w];
      r1[w] = supp[(64 + lane) * 5 + w];
      r2[w] = supp[(128 + lane) * 5 + w];
      r3[w] = supp[(192 + lane) * 5 + w];
    }
    ull k0 = kw[0], k1 = kw[1], k2 = kw[2], k3 = kw[3];
    ull f0 = 0, f1 = 0, f2 = 0, f3 = 0;
    int run = 0;
#define SCAN_CHUNK(R, KT, FT)                                              \
    for (int ib = 0; ib < 64; ++ib) {                                      \
      if ((KT >> ib) & 1ull) {                                             \
        k0 &= ~bcast64(R[0], ib); k1 &= ~bcast64(R[1], ib);                \
        k2 &= ~bcast64(R[2], ib); k3 &= ~bcast64(R[3], ib);                \
        if (++run <= MAXPC) FT |= (1ull << ib);                            \
      }                                                                    \
    }
    SCAN_CHUNK(r0, k0, f0)
    SCAN_CHUNK(r1, k1, f1)
    SCAN_CHUNK(r2, k2, f2)
    SCAN_CHUNK(r3, k3, f3)
#undef SCAN_CHUNK
    if (lane == 0) { kfw[0] = f0; kfw[1] = f1; kfw[2] = f2; kfw[3] = f3; }
  }
  __syncthreads();

  // compact kept entries to g_ks
  {
    ull w0 = kfw[0], w1 = kfw[1], w2 = kfw[2], w3 = kfw[3];
    int wq = tid >> 6, wb2 = tid & 63;
    ull myw = (wq == 0) ? w0 : (wq == 1) ? w1 : (wq == 2) ? w2 : w3;
    bool kept = (myw >> wb2) & 1ull;
    if (kept) {
      ull lt = (wb2 == 0) ? 0ull : (myw & ((1ull << wb2) - 1ull));
      int rank = __popcll(lt);
      if (wq > 0) rank += __popcll(w0);
      if (wq > 1) rank += __popcll(w1);
      if (wq > 2) rank += __popcll(w2);
      unsigned key = (unsigned)(v >> 32);
      unsigned n = (~(unsigned)v) & 0x3FFFu;
      ull e = ((ull)(key - KEYBASE) << 40) | ((ull)(unsigned)(127 - c) << 33) |
              ((ull)(unsigned)(255 - tid) << 25) | n;
      g_ks[(size_t)bc * MAXPC + rank] = e;
    }
    if (tid == 0)
      g_kcnt[bc] = (unsigned)(__popcll(w0) + __popcll(w1) + __popcll(w2) + __popcll(w3));
  }
}

// ---------- Kernel C1: merge 8 classes -> top-100 sorted ----------
__global__ __launch_bounds__(256)
void nms_merge8()
{
  const int tid = threadIdx.x;
  const int b = blockIdx.x / 10, g = blockIdx.x % 10;
  __shared__ ull le[8 * MAXPC];
  __shared__ ull cand[128];
  __shared__ unsigned kc[8], ko[9];
  __shared__ unsigned hist4[1024], suf[256], s_sel[2], wtot[4];
  __shared__ int s_cgt, s_ceq;

  if (tid < 8) kc[tid] = g_kcnt[b * NC + g * 8 + tid];
  if (tid < 128) cand[tid] = 0ull;
  __syncthreads();
  if (tid == 0) { unsigned a = 0; for (int i = 0; i < 8; ++i) { ko[i] = a; a += kc[i]; } ko[8] = a; }
  __syncthreads();
  const int total = (int)ko[8];

  for (int s = tid; s < 8 * MAXPC; s += 256) {
    int c8 = s / MAXPC, j = s - c8 * MAXPC;
    if (j < (int)kc[c8]) le[ko[c8] + j] = g_ks[(size_t)(b * NC + g * 8 + c8) * MAXPC + j];
  }
  __syncthreads();

  if (total <= MAXTOT) {
    if (tid < total) cand[tid] = le[tid];
  } else {
    unsigned T, need;
    auto gk = [&](int i) { return (unsigned)(le[i] >> 40); };
    radix_sel24(gk, total, MAXTOT, hist4, suf, s_sel, wtot, T, need);
    if (tid == 0) { s_cgt = 0; s_ceq = 0; }
    __syncthreads();
    const int ngt = MAXTOT - (int)need;
    for (int i = tid; i < total; i += 256) {
      unsigned k = (unsigned)(le[i] >> 40);
      if (k > T) cand[atomicAdd(&s_cgt, 1)] = le[i];
      else if (k == T) { int p = atomicAdd(&s_ceq, 1); if (p < (int)need) cand[ngt + p] = le[i]; }
    }
  }
  __syncthreads();

  for (int kk = 2; kk <= 128; kk <<= 1) {
    for (int j = kk >> 1; j > 0; j >>= 1) {
      if (tid < 128) {
        int ixj = tid ^ j;
        if (ixj > tid) {
          ull a = cand[tid], c2 = cand[ixj];
          if (((tid & kk) == 0) ? (a < c2) : (a > c2)) { cand[tid] = c2; cand[ixj] = a; }
        }
      }
      __syncthreads();
    }
  }
  if (tid < MAXTOT) g_ms[(size_t)(b * 10 + g) * MAXTOT + tid] = cand[tid];
  if (tid == 0) g_mcnt[b * 10 + g] = (unsigned)(total < MAXTOT ? total : MAXTOT);
}

// ---------- Kernel C2: merge 10 groups -> final output ----------
__global__ __launch_bounds__(256)
void nms_final(const float* __restrict__ b1, const float* __restrict__ b2,
               const float* __restrict__ b3, float* __restrict__ out)
{
  const int tid = threadIdx.x;
  const int b = blockIdx.x;
  __shared__ ull me[10 * MAXTOT];
  __shared__ ull cand[128];
  __shared__ unsigned mc[10], mo[11];
  __shared__ unsigned hist4[1024], suf[256], s_sel[2], wtot[4];
  __shared__ int s_cgt, s_ceq;

  if (tid < 10) mc[tid] = g_mcnt[b * 10 + tid];
  if (tid < 128) cand[tid] = 0ull;
  __syncthreads();
  if (tid == 0) { unsigned a = 0; for (int i = 0; i < 10; ++i) { mo[i] = a; a += mc[i]; } mo[10] = a; }
  __syncthreads();
  const int total = (int)mo[10];

  for (int s = tid; s < 10 * MAXTOT; s += 256) {
    int c10 = s / MAXTOT, j = s - c10 * MAXTOT;
    if (j < (int)mc[c10]) me[mo[c10] + j] = g_ms[(size_t)(b * 10 + c10) * MAXTOT + j];
  }
  __syncthreads();

  if (total <= MAXTOT) {
    if (tid < total) cand[tid] = me[tid];
  } else {
    unsigned T, need;
    auto gk = [&](int i) { return (unsigned)(me[i] >> 40); };
    radix_sel24(gk, total, MAXTOT, hist4, suf, s_sel, wtot, T, need);
    if (tid == 0) { s_cgt = 0; s_ceq = 0; }
    __syncthreads();
    const int ngt = MAXTOT - (int)need;
    for (int i = tid; i < total; i += 256) {
      unsigned k = (unsigned)(me[i] >> 40);
      if (k > T) cand[atomicAdd(&s_cgt, 1)] = me[i];
      else if (k == T) { int p = atomicAdd(&s_ceq, 1); if (p < (int)need) cand[ngt + p] = me[i]; }
    }
  }
  __syncthreads();

  for (int kk = 2; kk <= 128; kk <<= 1) {
    for (int j = kk >> 1; j > 0; j >>= 1) {
      if (tid < 128) {
        int ixj = tid ^ j;
        if (ixj > tid) {
          ull a = cand[tid], c2 = cand[ixj];
          if (((tid & kk) == 0) ? (a < c2) : (a > c2)) { cand[tid] = c2; cand[ixj] = a; }
        }
      }
      __syncthreads();
    }
  }

  if (tid < MAXTOT) {
    ull e = cand[tid];
    float o0 = 0.f, o1 = 0.f, o2 = 0.f, o3 = 0.f, osc = 0.f, ocl = 0.f;
    if (e != 0ull) {
      unsigned key24 = (unsigned)(e >> 40);
      float sc = inv_okey(key24 + KEYBASE);
      int cls = 127 - (int)((e >> 33) & 127u);
      int n = (int)(e & 0x3FFFu);
      const float* bp;
      if (n < NA1)            bp = b1 + (size_t)(b * NA1 + n) * 4;
      else if (n < NA1 + NA2) bp = b2 + (size_t)(b * NA2 + (n - NA1)) * 4;
      else                    bp = b3 + (size_t)(b * NA3 + (n - NA1 - NA2)) * 4;
      o0 = fminf(fmaxf(bp[0], 0.0f), 1.0f);
      o1 = fminf(fmaxf(bp[1], 0.0f), 1.0f);
      o2 = fminf(fmaxf(bp[2], 0.0f), 1.0f);
      o3 = fminf(fmaxf(bp[3], 0.0f), 1.0f);
      osc = sc; ocl = (float)cls;
    }
    int oi = b * MAXTOT + tid;
    out[(size_t)oi * 4 + 0] = o0;
    out[(size_t)oi * 4 + 1] = o1;
    out[(size_t)oi * 4 + 2] = o2;
    out[(size_t)oi * 4 + 3] = o3;
    out[BATCH * MAXTOT * 4 + oi] = osc;
    out[BATCH * MAXTOT * 5 + oi] = ocl;
  }
  if (tid == 0) out[BATCH * MAXTOT * 6 + b] = (float)(total < MAXTOT ? total : MAXTOT);
}

extern "C" void kernel_launch(void* const* d_in, const int* in_sizes, int n_in,
                              void* d_out, int out_size, void* d_ws, size_t ws_size,
                              hipStream_t stream) {
  const float* b1 = (const float*)d_in[0];
  const float* c1 = (const float*)d_in[1];
  const float* p1 = (const float*)d_in[2];
  const float* b2 = (const float*)d_in[3];
  const float* c2 = (const float*)d_in[4];
  const float* p2 = (const float*)d_in[5];
  const float* b3 = (const float*)d_in[6];
  const float* c3 = (const float*)d_in[7];
  const float* p3 = (const float*)d_in[8];
  (void)in_sizes; (void)n_in; (void)out_size; (void)d_ws; (void)ws_size;

  score_compact<<<dim3(BATCH * NTILES), dim3(256), 0, stream>>>(c1, p1, c2, p2, c3, p3);
  nms_per_class<<<dim3(BATCH * NC), dim3(256), 0, stream>>>(b1, b2, b3);
  nms_merge8<<<dim3(BATCH * 10), dim3(256), 0, stream>>>();
  nms_final<<<dim3(BATCH), dim3(256), 0, stream>>>(b1, b2, b3, (float*)d_out);
}

// Round 9
// 227.759 us; speedup vs baseline: 1.6630x; 1.0612x over previous
//
#include <hip/hip_runtime.h>
#include <stdint.h>

#define BATCH 8
#define NC 80
#define NA1 8112
#define NA2 2028
#define NA3 507
#define NTOT 10647
#define TILE 64
#define NTILES 167           /* ceil(10647/64) */
#define NSLOTS (NTILES*TILE) /* 10688 */
#define KSEL 256
#define MAXPC 100
#define MAXTOT 100
#define SCTHR 0.3f
#define IOUTHR 0.5f
#define KEYTHR 0xBE99999Au   /* okey(0.3f): candidate iff key > KEYTHR */
#define KEYBASE 0xBE99999Bu  /* rebased keys fit in 24 bits */
#define STAGE_CAP 4608       /* ~20 sigma above E[cnt]=3607 for this distribution */

typedef unsigned long long ull;

// static device scratch; every word read was written THIS launch
__device__ ull g_cand[(size_t)BATCH * NC * NSLOTS];   // 54.7 MB
__device__ unsigned g_tcnt[BATCH * NC * NTILES];      // per (class,tile) counts
__device__ ull g_ks[BATCH * NC * MAXPC];              // per-class kept, packed
__device__ unsigned g_kcnt[BATCH * NC];

__device__ __forceinline__ unsigned okey(float f) {
  unsigned u = __float_as_uint(f);
  return u ^ ((unsigned)((int)u >> 31) | 0x80000000u);
}
__device__ __forceinline__ float inv_okey(unsigned k) {
  unsigned u = (k & 0x80000000u) ? (k ^ 0x80000000u) : ~k;
  return __uint_as_float(u);
}
__device__ __forceinline__ ull shflxor64(ull v, int m) {
  int lo = __shfl_xor((int)(unsigned)v, m, 64);
  int hi = __shfl_xor((int)(unsigned)(v >> 32), m, 64);
  return ((ull)(unsigned)hi << 32) | (unsigned)lo;
}
__device__ __forceinline__ ull bcast64(ull v, int src) {
  int lo = __shfl((int)(unsigned)v, src, 64);
  int hi = __shfl((int)(unsigned)(v >> 32), src, 64);
  return ((ull)(unsigned)hi << 32) | (unsigned)lo;
}
__device__ __forceinline__ unsigned wave_sufscan(unsigned v, int lane) {
  #pragma unroll
  for (int off = 1; off < 64; off <<= 1) {
    unsigned t = __shfl_down(v, off, 64);
    if (lane + off < 64) v += t;
  }
  return v;
}

// top-kwant threshold over rebased 24-bit keys. getkey returns 0xFFFFFFFF = skip.
template <typename F>
__device__ void radix_sel24(F getkey, int n, unsigned kwant,
                            unsigned* hist4, unsigned* suf,
                            unsigned* s_sel, unsigned* wtot,
                            unsigned& T_out, unsigned& need_out)
{
  const int tid = threadIdx.x;
  const int lane = tid & 63, wv = tid >> 6;
  const int wb = wv << 8;
  unsigned need = kwant, prefix = 0;
  for (int shift = 16; shift >= 0; shift -= 8) {
    hist4[tid] = 0; hist4[tid + 256] = 0; hist4[tid + 512] = 0; hist4[tid + 768] = 0;
    __syncthreads();
    unsigned maskhi = (shift == 16) ? 0u : (0x00FFFFFFu ^ ((1u << (shift + 8)) - 1u));
    #pragma unroll 4
    for (int i = tid; i < n; i += 256) {
      unsigned k = getkey(i);
      if (k != 0xFFFFFFFFu && (k & maskhi) == prefix)
        atomicAdd(&hist4[wb + ((k >> shift) & 255u)], 1u);
    }
    __syncthreads();
    unsigned v = hist4[tid] + hist4[tid + 256] + hist4[tid + 512] + hist4[tid + 768];
    v = wave_sufscan(v, lane);
    if (lane == 0) wtot[wv] = v;
    __syncthreads();
    unsigned add = 0;
    for (int w = wv + 1; w < 4; ++w) add += wtot[w];
    v += add;
    suf[tid] = v;
    __syncthreads();
    unsigned nxt = (tid == 255) ? 0u : suf[tid + 1];
    if (v >= need && nxt < need) {
      s_sel[0] = prefix | ((unsigned)tid << shift);
      s_sel[1] = need - nxt;
    }
    __syncthreads();
    prefix = s_sel[0]; need = s_sel[1];
    __syncthreads();
  }
  T_out = prefix; need_out = need;
}

// ---------- Kernel A: scores + per-(class,tile) compaction, no atomics ----------
__global__ __launch_bounds__(256)
void score_compact(const float* __restrict__ c1, const float* __restrict__ p1,
                   const float* __restrict__ c2, const float* __restrict__ p2,
                   const float* __restrict__ c3, const float* __restrict__ p3)
{
  const int tid = threadIdx.x;
  const int b = blockIdx.x / NTILES;
  const int t = blockIdx.x % NTILES;
  const int n0 = t * TILE;

  __shared__ float sp[TILE * 81];

  for (int e4 = tid; e4 < TILE * 20; e4 += 256) {
    int a = e4 / 20;
    int c4 = (e4 - a * 20) * 4;
    int ng = n0 + a;
    if (ng < NTOT) {
      const float* pp; int nl;
      if (ng < NA1)            { pp = p1 + (size_t)b * NA1 * NC; nl = ng; }
      else if (ng < NA1 + NA2) { pp = p2 + (size_t)b * NA2 * NC; nl = ng - NA1; }
      else                     { pp = p3 + (size_t)b * NA3 * NC; nl = ng - NA1 - NA2; }
      float4 pv = *(const float4*)(pp + (size_t)nl * NC + c4);
      sp[a * 81 + c4 + 0] = pv.x; sp[a * 81 + c4 + 1] = pv.y;
      sp[a * 81 + c4 + 2] = pv.z; sp[a * 81 + c4 + 3] = pv.w;
    }
  }
  __syncthreads();

  const int wv = tid >> 6, lane = tid & 63;
  const int ng = n0 + lane;
  const bool av = ng < NTOT;
  float cf = 0.0f;
  if (av) {
    if (ng < NA1)            cf = c1[b * NA1 + ng];
    else if (ng < NA1 + NA2) cf = c2[b * NA2 + ng - NA1];
    else                     cf = c3[b * NA3 + ng - NA1 - NA2];
  }
  for (int k = 0; k < 20; ++k) {
    int c = wv + 4 * k;
    float pv = av ? sp[lane * 81 + c] : 0.0f;
    unsigned key = okey(pv * cf);
    bool pred = av && (key > KEYTHR);
    ull m = __ballot(pred);
    if (pred) {
      unsigned pos = (unsigned)__popcll(m & ((1ull << lane) - 1ull));
      g_cand[((size_t)(b * NC + c) * NTILES + t) * TILE + pos] =
          ((ull)key << 32) | (unsigned)(~ng);
    }
    if (lane == 0) g_tcnt[(b * NC + c) * NTILES + t] = (unsigned)__popcll(m);
  }
}

// ---------- Kernel B: per (b,c) top-256 + sort + NMS ----------
__global__ __launch_bounds__(256)
void nms_per_class(const float* __restrict__ b1, const float* __restrict__ b2,
                   const float* __restrict__ b3)
{
  const int tid = threadIdx.x;
  const int lane = tid & 63, wv = tid >> 6;
  const int bc = blockIdx.x;
  const int b = bc / NC;
  const int c = bc - b * NC;

  __shared__ ull cstage[STAGE_CAP];            // 36864 B; aliased below after death
  __shared__ unsigned tc[NTILES];              // 668 B
  __shared__ unsigned off[NTILES + 1];         // 672 B
  __shared__ unsigned hist4[1024];             // 4096 B
  __shared__ unsigned suf[256];                // 1024 B
  __shared__ ull cand[KSEL];                   // 2048 B
  __shared__ ull kw[4], kfw[4];
  __shared__ unsigned s_sel[2], wtot[4];
  __shared__ int s_cgt, s_ceq;
  // aliases into cstage (cstage dead after compaction):
  ull* supp = cstage;                                   // 256*5*8 = 10240 B
  float4* cbox = (float4*)((char*)cstage + 10240);      // 4096 B

  const ull* crow = g_cand + (size_t)bc * NSLOTS;
  const unsigned* trow = g_tcnt + bc * NTILES;

  cand[tid] = 0ull;
  if (tid == 0) { s_cgt = 0; s_ceq = 0; }
  if (tid < NTILES) tc[tid] = trow[tid];
  __syncthreads();

  if (wv == 0) {                               // exclusive prefix over 167 counts
    unsigned carry = 0;
    for (int ch = 0; ch < 3; ++ch) {
      int idx = ch * 64 + lane;
      unsigned x = (idx < NTILES) ? tc[idx] : 0u;
      unsigned v = x;
      #pragma unroll
      for (int o = 1; o < 64; o <<= 1) {
        unsigned t2 = __shfl_up(v, o, 64);
        if (lane >= o) v += t2;
      }
      if (idx < NTILES) off[idx] = carry + v - x;
      carry += (unsigned)__shfl((int)v, 63, 64);
    }
    if (lane == 0) off[NTILES] = carry;
  }
  __syncthreads();
  const int cnt = (int)off[NTILES];
  const bool staged = (cnt > KSEL) && (cnt <= STAGE_CAP);

  // staging: chunked 8-wide so loads overlap (latency-bound at idle clocks)
  for (int base = 0; base < NSLOTS; base += 2048) {
    ull v[8]; int pos[8]; bool ok[8];
    #pragma unroll
    for (int e = 0; e < 8; ++e) {
      int s = base + e * 256 + tid;
      ok[e] = false;
      if (s < NSLOTS) {
        int t = s >> 6, j = s & 63;
        if (j < (int)tc[t]) { ok[e] = true; pos[e] = (int)off[t] + j; v[e] = crow[s]; }
      }
    }
    #pragma unroll
    for (int e = 0; e < 8; ++e) {
      if (ok[e]) {
        if (cnt <= KSEL) cand[pos[e]] = v[e];
        else if (staged) cstage[pos[e]] = v[e];
      }
    }
  }
  __syncthreads();

  if (cnt > KSEL) {
    unsigned T, need;
    if (staged) {
      auto gk = [&](int i) { return (unsigned)(cstage[i] >> 32) - KEYBASE; };
      radix_sel24(gk, cnt, KSEL, hist4, suf, s_sel, wtot, T, need);
    } else {
      auto gk = [&](int s) {
        int t = s >> 6, j = s & 63;
        return (j < (int)tc[t]) ? ((unsigned)(crow[s] >> 32) - KEYBASE) : 0xFFFFFFFFu;
      };
      radix_sel24(gk, NSLOTS, KSEL, hist4, suf, s_sel, wtot, T, need);
    }
    const int ngt = KSEL - (int)need;
    if (staged) {
      // ballot-aggregated compaction: 2 LDS atomics per wave per iteration
      const int cntPad = (cnt + 255) & ~255;
      for (int i = tid; i < cntPad; i += 256) {
        ull v = (i < cnt) ? cstage[i] : 0ull;
        unsigned k = (unsigned)(v >> 32) - KEYBASE;
        bool g = (i < cnt) && (k > T);
        bool q = (i < cnt) && (k == T);
        ull mg = __ballot(g), mq = __ballot(q);
        unsigned bg = 0, bq = 0;
        if (lane == 0) {
          if (mg) bg = (unsigned)atomicAdd(&s_cgt, (int)__popcll(mg));
          if (mq) bq = (unsigned)atomicAdd(&s_ceq, (int)__popcll(mq));
        }
        bg = (unsigned)__shfl((int)bg, 0, 64);
        bq = (unsigned)__shfl((int)bq, 0, 64);
        ull lt = (1ull << lane) - 1ull;
        if (g) cand[bg + __popcll(mg & lt)] = v;
        if (q) { int p = (int)(bq + __popcll(mq & lt)); if (p < (int)need) cand[ngt + p] = v; }
      }
    } else {
      for (int s = tid; s < NSLOTS; s += 256) {
        int t = s >> 6, j = s & 63;
        if (j < (int)tc[t]) {
          ull v = crow[s];
          unsigned k = (unsigned)(v >> 32) - KEYBASE;
          if (k > T) cand[atomicAdd(&s_cgt, 1)] = v;
          else if (k == T) { int p = atomicAdd(&s_ceq, 1); if (p < (int)need) cand[ngt + p] = v; }
        }
      }
    }
  }
  __syncthreads();

  // bitonic sort 256 descending: registers + shfl; LDS only for j>=64
  ull v = cand[tid];
  for (int kk = 2; kk <= KSEL; kk <<= 1) {
    for (int j = kk >> 1; j > 0; j >>= 1) {
      ull o;
      if (j >= 64) {
        cand[tid] = v;
        __syncthreads();
        o = cand[tid ^ j];
        __syncthreads();
      } else {
        o = shflxor64(v, j);
      }
      bool keep_max = (((tid & j) == 0) == ((tid & kk) == 0));
      v = keep_max ? (v > o ? v : o) : (v < o ? v : o);
    }
  }
  __syncthreads();   // cstage dead from here; supp/cbox aliases safe

  {
    float4 bx = make_float4(0.f, 0.f, 0.f, 0.f);
    if (v != 0ull) {
      int myn = (int)(~(unsigned)v);
      const float* bp;
      if (myn < NA1)            bp = b1 + (size_t)(b * NA1 + myn) * 4;
      else if (myn < NA1 + NA2) bp = b2 + (size_t)(b * NA2 + (myn - NA1)) * 4;
      else                      bp = b3 + (size_t)(b * NA3 + (myn - NA1 - NA2)) * 4;
      bx = make_float4(bp[0], bp[1], bp[2], bp[3]);
    }
    cbox[tid] = bx;
  }
  ull mvalid = __ballot(v != 0ull);
  if (lane == 0) kw[wv] = mvalid;
  __syncthreads();

  // suppression rows (thread i: bits j>i with iou>thr)
  {
    const float4 mb = cbox[tid];
    const float myarea = (mb.z - mb.x) * (mb.w - mb.y);
    ull m0 = 0, m1 = 0, m2 = 0, m3 = 0;
    #pragma unroll 8
    for (int j = 0; j < KSEL; ++j) {
      float4 bj = cbox[j];
      float ja = (bj.z - bj.x) * (bj.w - bj.y);
      float iy = fmaxf(fminf(bj.z, mb.z) - fmaxf(bj.x, mb.x), 0.0f);
      float ix = fmaxf(fminf(bj.w, mb.w) - fmaxf(bj.y, mb.y), 0.0f);
      float inter = iy * ix;
      float uni = ja + myarea - inter;
      bool sup = (j > tid) && (uni > 0.0f) && (inter > IOUTHR * uni);
      ull bit = sup ? (1ull << (j & 63)) : 0ull;
      if ((j >> 6) == 0) m0 |= bit; else if ((j >> 6) == 1) m1 |= bit;
      else if ((j >> 6) == 2) m2 |= bit; else m3 |= bit;
    }
    supp[tid * 5 + 0] = m0; supp[tid * 5 + 1] = m1;
    supp[tid * 5 + 2] = m2; supp[tid * 5 + 3] = m3;
  }
  __syncthreads();

  // greedy scan, wave 0, registers only; early break at 100 kept
  if (wv == 0) {
    ull r0[4], r1[4], r2[4], r3[4];
    #pragma unroll
    for (int w = 0; w < 4; ++w) {
      r0[w] = supp[(lane) * 5 + w];
      r1[w] = supp[(64 + lane) * 5 + w];
      r2[w] = supp[(128 + lane) * 5 + w];
      r3[w] = supp[(192 + lane) * 5 + w];
    }
    ull k0 = kw[0], k1 = kw[1], k2 = kw[2], k3 = kw[3];
    ull f0 = 0, f1 = 0, f2 = 0, f3 = 0;
    int run = 0;
#define SCAN_CHUNK(R, KT, FT)                                              \
    if (KT) for (int ib = 0; ib < 64; ++ib) {                              \
      if ((KT >> ib) & 1ull) {                                             \
        k0 &= ~bcast64(R[0], ib); k1 &= ~bcast64(R[1], ib);                \
        k2 &= ~bcast64(R[2], ib); k3 &= ~bcast64(R[3], ib);                \
        FT |= (1ull << ib);                                                \
        if (++run == MAXPC) goto scan_done;                                \
      }                                                                    \
    }
    SCAN_CHUNK(r0, k0, f0)
    SCAN_CHUNK(r1, k1, f1)
    SCAN_CHUNK(r2, k2, f2)
    SCAN_CHUNK(r3, k3, f3)
#undef SCAN_CHUNK
scan_done:
    if (lane == 0) { kfw[0] = f0; kfw[1] = f1; kfw[2] = f2; kfw[3] = f3; }
  }
  __syncthreads();

  // compact kept entries to g_ks
  {
    ull w0 = kfw[0], w1 = kfw[1], w2 = kfw[2], w3 = kfw[3];
    int wq = tid >> 6, wb2 = tid & 63;
    ull myw = (wq == 0) ? w0 : (wq == 1) ? w1 : (wq == 2) ? w2 : w3;
    bool kept = (myw >> wb2) & 1ull;
    if (kept) {
      ull lt = (wb2 == 0) ? 0ull : (myw & ((1ull << wb2) - 1ull));
      int rank = __popcll(lt);
      if (wq > 0) rank += __popcll(w0);
      if (wq > 1) rank += __popcll(w1);
      if (wq > 2) rank += __popcll(w2);
      unsigned key = (unsigned)(v >> 32);
      unsigned n = (~(unsigned)v) & 0x3FFFu;
      ull e = ((ull)(key - KEYBASE) << 40) | ((ull)(unsigned)(127 - c) << 33) |
              ((ull)(unsigned)(255 - tid) << 25) | n;
      g_ks[(size_t)bc * MAXPC + rank] = e;
    }
    if (tid == 0)
      g_kcnt[bc] = (unsigned)(__popcll(w0) + __popcll(w1) + __popcll(w2) + __popcll(w3));
  }
}

// ---------- Kernel C: per-image merge of 80 classes -> top-100 + output ----------
__global__ __launch_bounds__(256)
void nms_final(const float* __restrict__ b1, const float* __restrict__ b2,
               const float* __restrict__ b3, float* __restrict__ out)
{
  const int tid = threadIdx.x;
  const int lane = tid & 63, wv = tid >> 6;
  const int b = blockIdx.x;
  __shared__ ull le[NC * MAXPC];               // 64000 B
  __shared__ ull cand[128];
  __shared__ unsigned kc[NC], ko[NC + 1];
  __shared__ unsigned hist4[1024], suf[256], s_sel[2], wtot[4];
  __shared__ int s_cgt, s_ceq;

  if (tid < NC) kc[tid] = g_kcnt[b * NC + tid];
  if (tid < 128) cand[tid] = 0ull;
  if (tid == 0) { s_cgt = 0; s_ceq = 0; }
  __syncthreads();

  if (wv == 0) {                               // exclusive prefix over 80 counts
    unsigned carry = 0;
    for (int ch = 0; ch < 2; ++ch) {
      int idx = ch * 64 + lane;
      unsigned x = (idx < NC) ? kc[idx] : 0u;
      unsigned v = x;
      #pragma unroll
      for (int o = 1; o < 64; o <<= 1) {
        unsigned t2 = __shfl_up(v, o, 64);
        if (lane >= o) v += t2;
      }
      if (idx < NC) ko[idx] = carry + v - x;
      carry += (unsigned)__shfl((int)v, 63, 64);
    }
    if (lane == 0) ko[NC] = carry;
  }
  __syncthreads();
  const int total = (int)ko[NC];

  #pragma unroll 4
  for (int s = tid; s < NC * MAXPC; s += 256) {
    int c8 = s / MAXPC, j = s - c8 * MAXPC;
    if (j < (int)kc[c8]) le[ko[c8] + j] = g_ks[(size_t)(b * NC + c8) * MAXPC + j];
  }
  __syncthreads();

  if (total <= MAXTOT) {
    if (tid < total) cand[tid] = le[tid];
  } else {
    unsigned T, need;
    auto gk = [&](int i) { return (unsigned)(le[i] >> 40); };
    radix_sel24(gk, total, MAXTOT, hist4, suf, s_sel, wtot, T, need);
    const int ngt = MAXTOT - (int)need;
    const int totPad = (total + 255) & ~255;
    for (int i = tid; i < totPad; i += 256) {
      ull v = (i < total) ? le[i] : 0ull;
      unsigned k = (unsigned)(v >> 40);
      bool g = (i < total) && (k > T);
      bool q = (i < total) && (k == T);
      ull mg = __ballot(g), mq = __ballot(q);
      unsigned bg = 0, bq = 0;
      if (lane == 0) {
        if (mg) bg = (unsigned)atomicAdd(&s_cgt, (int)__popcll(mg));
        if (mq) bq = (unsigned)atomicAdd(&s_ceq, (int)__popcll(mq));
      }
      bg = (unsigned)__shfl((int)bg, 0, 64);
      bq = (unsigned)__shfl((int)bq, 0, 64);
      ull lt = (1ull << lane) - 1ull;
      if (g) cand[bg + __popcll(mg & lt)] = v;
      if (q) { int p = (int)(bq + __popcll(mq & lt)); if (p < (int)need) cand[ngt + p] = v; }
    }
  }
  __syncthreads();

  for (int kk = 2; kk <= 128; kk <<= 1) {
    for (int j = kk >> 1; j > 0; j >>= 1) {
      if (tid < 128) {
        int ixj = tid ^ j;
        if (ixj > tid) {
          ull a = cand[tid], c2 = cand[ixj];
          if (((tid & kk) == 0) ? (a < c2) : (a > c2)) { cand[tid] = c2; cand[ixj] = a; }
        }
      }
      __syncthreads();
    }
  }

  if (tid < MAXTOT) {
    ull e = cand[tid];
    float o0 = 0.f, o1 = 0.f, o2 = 0.f, o3 = 0.f, osc = 0.f, ocl = 0.f;
    if (e != 0ull) {
      unsigned key24 = (unsigned)(e >> 40);
      float sc = inv_okey(key24 + KEYBASE);
      int cls = 127 - (int)((e >> 33) & 127u);
      int n = (int)(e & 0x3FFFu);
      const float* bp;
      if (n < NA1)            bp = b1 + (size_t)(b * NA1 + n) * 4;
      else if (n < NA1 + NA2) bp = b2 + (size_t)(b * NA2 + (n - NA1)) * 4;
      else                    bp = b3 + (size_t)(b * NA3 + (n - NA1 - NA2)) * 4;
      o0 = fminf(fmaxf(bp[0], 0.0f), 1.0f);
      o1 = fminf(fmaxf(bp[1], 0.0f), 1.0f);
      o2 = fminf(fmaxf(bp[2], 0.0f), 1.0f);
      o3 = fminf(fmaxf(bp[3], 0.0f), 1.0f);
      osc = sc; ocl = (float)cls;
    }
    int oi = b * MAXTOT + tid;
    out[(size_t)oi * 4 + 0] = o0;
    out[(size_t)oi * 4 + 1] = o1;
    out[(size_t)oi * 4 + 2] = o2;
    out[(size_t)oi * 4 + 3] = o3;
    out[BATCH * MAXTOT * 4 + oi] = osc;
    out[BATCH * MAXTOT * 5 + oi] = ocl;
  }
  if (tid == 0) out[BATCH * MAXTOT * 6 + b] = (float)(total < MAXTOT ? total : MAXTOT);
}

extern "C" void kernel_launch(void* const* d_in, const int* in_sizes, int n_in,
                              void* d_out, int out_size, void* d_ws, size_t ws_size,
                              hipStream_t stream) {
  const float* b1 = (const float*)d_in[0];
  const float* c1 = (const float*)d_in[1];
  const float* p1 = (const float*)d_in[2];
  const float* b2 = (const float*)d_in[3];
  const float* c2 = (const float*)d_in[4];
  const float* p2 = (const float*)d_in[5];
  const float* b3 = (const float*)d_in[6];
  const float* c3 = (const float*)d_in[7];
  const float* p3 = (const float*)d_in[8];
  (void)in_sizes; (void)n_in; (void)out_size; (void)d_ws; (void)ws_size;

  score_compact<<<dim3(BATCH * NTILES), dim3(256), 0, stream>>>(c1, p1, c2, p2, c3, p3);
  nms_per_class<<<dim3(BATCH * NC), dim3(256), 0, stream>>>(b1, b2, b3);
  nms_final<<<dim3(BATCH), dim3(256), 0, stream>>>(b1, b2, b3, (float*)d_out);
}